// Round 10
// baseline (305.438 us; speedup 1.0000x reference)
//
#include <hip/hip_runtime.h>
#include <hip/hip_cooperative_groups.h>

namespace cg = cooperative_groups;

#define NUM_NODES 50000
#define WINDOW 8
#define DIM 256
#define BATCH 8192
#define NROWS (NUM_NODES * WINDOW)          // 400000 rows
#define ROW4  (DIM / 4)                     // 64 float4 per row
#define BANK4 ((long)NROWS * ROW4)          // 25.6M float4
#define TS4   (NROWS / 4)                   // 100K float4

#define GRID   1024                         // 4 blocks/CU -> cooperative residency safe
#define NTHR   (GRID * 256)                 // 262144 threads
#define NWAVE  (NTHR / 64)                  // 4096 waves
#define QPW    (BATCH / NWAVE)              // 2 batch elements per wave (static)

typedef float f4 __attribute__((ext_vector_type(4)));

// ONE kernel, ONE graph node, ZERO workspace.
// A: wave-parallel (c, rank) scan of idx, results in registers.
// B: pure streaming copy (the HBM floor) + out_ptr prefill.
// sync. C: winner waves overwrite row/ts/ptr.
__global__ void __launch_bounds__(256, 4)
mono_kernel(const f4* __restrict__ bank4, const f4* __restrict__ ts4,
            const f4* __restrict__ nrep4, const float* __restrict__ t,
            const int* __restrict__ ptr, const int* __restrict__ idx,
            f4* __restrict__ out_bank4, f4* __restrict__ out_ts4,
            float* __restrict__ out_ptr) {
    const int  tid    = blockIdx.x * 256 + threadIdx.x;
    const int  lane   = threadIdx.x & 63;
    const int  waveid = tid >> 6;
    const int4* idx4  = (const int4*)idx;

    // ---- phase A: (c, rank) for bi = waveid + q*NWAVE, q = 0..1 --------------------
    // rank = #{j < bi : idx[j]==idx[bi]}; c = total occurrences. Coalesced scan:
    // lane l reads int4 k = it*64+l (32 iters over 8192 ints), shfl-xor reduce.
    int rowQ[QPW], pnewQ[QPW], nodeQ[QPW];
    #pragma unroll
    for (int q = 0; q < QPW; ++q) {
        const int bi   = waveid + q * NWAVE;
        const int node = idx[bi];                       // broadcast load
        int c = 0, r = 0;
        for (int k = lane; k < BATCH / 4; k += 64) {
            int4 v   = idx4[k];
            int base = 4 * k;
            c += (v.x == node) + (v.y == node) + (v.z == node) + (v.w == node);
            r += (v.x == node && base     < bi) + (v.y == node && base + 1 < bi)
               + (v.z == node && base + 2 < bi) + (v.w == node && base + 3 < bi);
        }
        int packed = (c << 16) | r;                     // c<=8192 fits; sum < 2^30
        #pragma unroll
        for (int off = 32; off; off >>= 1) packed += __shfl_xor(packed, off);
        c = packed >> 16;  r = packed & 0xffff;

        // winner iff r >= c-8 (last writer per slot); winners get distinct slots.
        rowQ[q]  = (r >= c - WINDOW) ? node * WINDOW + ((ptr[node] + r) & (WINDOW - 1))
                                     : -1;
        pnewQ[q] = (r == c - 1) ? (ptr[node] + c) : -1; // unique per touched node
        nodeQ[q] = node;
    }

    // ---- phase B: the HBM-bound streaming copy + ptr prefill -----------------------
    for (long i = tid; i < BANK4; i += NTHR) out_bank4[i] = bank4[i];
    for (int  i = tid; i < TS4;   i += NTHR) out_ts4[i]   = ts4[i];
    for (int  i = tid; i < NUM_NODES; i += NTHR) out_ptr[i] = (float)ptr[i];

    cg::this_grid().sync();

    // ---- phase C: overwrite winner rows / ts / ptr ---------------------------------
    float* out_ts = (float*)out_ts4;
    #pragma unroll
    for (int q = 0; q < QPW; ++q) {
        const int row = rowQ[q];
        const int bi  = waveid + q * NWAVE;
        if (row >= 0) {
            out_bank4[(long)row * ROW4 + lane] = nrep4[(long)bi * ROW4 + lane];
            if (lane == 0) out_ts[row] = t[bi];
        }
        if (lane == 0 && pnewQ[q] >= 0)
            out_ptr[nodeQ[q]] = (float)pnewQ[q];        // exact in f32 (<= ~1e6+8)
    }
}

extern "C" void kernel_launch(void* const* d_in, const int* in_sizes, int n_in,
                              void* d_out, int out_size, void* d_ws, size_t ws_size,
                              hipStream_t stream) {
    const f4*    bank4 = (const f4*)d_in[0];
    const f4*    ts4   = (const f4*)d_in[1];
    const f4*    nrep4 = (const f4*)d_in[2];
    const float* t     = (const float*)d_in[3];
    const int*   ptr   = (const int*)d_in[4];
    const int*   idx   = (const int*)d_in[5];

    f4*    out_bank4 = (f4*)d_out;
    f4*    out_ts4   = (f4*)((float*)d_out + (size_t)NUM_NODES * WINDOW * DIM);
    float* out_ptr   = (float*)d_out + (size_t)NUM_NODES * WINDOW * DIM
                                     + (size_t)NUM_NODES * WINDOW;

    void* args[] = { (void*)&bank4, (void*)&ts4, (void*)&nrep4, (void*)&t,
                     (void*)&ptr, (void*)&idx,
                     (void*)&out_bank4, (void*)&out_ts4, (void*)&out_ptr };

    hipLaunchCooperativeKernel((const void*)mono_kernel, dim3(GRID), dim3(256),
                               args, 0, stream);
}